// Round 1
// baseline (1293.911 us; speedup 1.0000x reference)
//
#include <hip/hip_runtime.h>
#include <math.h>

#define NB 64
#define NS 2048
#define ND 512
#define CCLIP 10.0f

// ---------------------------------------------------------------------------
// Kernel A: q[b,d] = sum_k W_q[d,k] * tgt[b,k]   (tiny: 64x512 outputs)
// grid = 128 (2 blocks per b), block = 256
// ---------------------------------------------------------------------------
__global__ __launch_bounds__(256) void qk_kernel(const float* __restrict__ tgt,
                                                 const float* __restrict__ Wq,
                                                 float* __restrict__ q_ws) {
  const int b = blockIdx.x >> 1;
  const int d = ((blockIdx.x & 1) << 8) + threadIdx.x;
  __shared__ float tl[ND];
  tl[threadIdx.x] = tgt[b * ND + threadIdx.x];
  tl[threadIdx.x + 256] = tgt[b * ND + threadIdx.x + 256];
  __syncthreads();
  const float4* wr = (const float4*)(Wq + (size_t)d * ND);
  float acc = 0.f;
#pragma unroll 8
  for (int k4 = 0; k4 < ND / 4; ++k4) {
    float4 w4 = wr[k4];
    acc += w4.x * tl[4 * k4 + 0] + w4.y * tl[4 * k4 + 1] +
           w4.z * tl[4 * k4 + 2] + w4.w * tl[4 * k4 + 3];
  }
  q_ws[b * ND + d] = acc;
}

// ---------------------------------------------------------------------------
// Kernel B (main, fused): per block = one batch b and 64 src rows.
//   r = src_tile @ W_ref^T   (fp32 LDS-tiled GEMM, 8 col-chunks x 8 k-tiles)
//   h = tanh(r + q[b,:]); u = h . v ; logit = C*tanh(u); w = exp(logit - C)
//   partial d' accumulation: dp[d] = sum_i w_i * src[i,d]  -> dp_ws
// LDS tiles use k-permuted transposed layout: element (kloc=4l+c, i) stored at
// row k' = l + 16c, stride 68 -> staging writes 2-way (free), b128 reads clean.
// ---------------------------------------------------------------------------
__global__ __launch_bounds__(256) void main_kernel(
    const float* __restrict__ src, const float* __restrict__ Wref,
    const float* __restrict__ v, const float* __restrict__ q_ws,
    float* __restrict__ w_ws, float* __restrict__ dp_ws,
    float* __restrict__ out_logit) {
  __shared__ __align__(16) float sA[64 * 68];
  __shared__ __align__(16) float sB[64 * 68];
  __shared__ float wrow[64];

  const int tid = threadIdx.x;
  const int blk = blockIdx.x;
  const int b = blk >> 5;         // 32 row-tiles per batch
  const int s0 = (blk & 31) << 6; // 64 rows per tile

  const int tj = tid & 15;  // output col group (4 cols)
  const int ti = tid >> 4;  // output row group (4 rows)

  const int l = tid & 15;   // staging: k-float4 index
  const int rb = tid >> 4;  // staging: row base

  const float4* src4 = (const float4*)src;
  const float4* W4 = (const float4*)Wref;

  float pu[4] = {0.f, 0.f, 0.f, 0.f};

  for (int jc = 0; jc < 8; ++jc) {
    float acc[4][4];
#pragma unroll
    for (int r = 0; r < 4; ++r)
#pragma unroll
      for (int c = 0; c < 4; ++c) acc[r][c] = 0.f;

    for (int kt = 0; kt < 8; ++kt) {
      __syncthreads();  // previous tile fully consumed
#pragma unroll
      for (int p = 0; p < 4; ++p) {
        const int row = rb + p * 16;
        float4 ga = src4[((size_t)(b * NS + s0 + row) * ND + kt * 64) / 4 + l];
        sA[(l + 0) * 68 + row] = ga.x;
        sA[(l + 16) * 68 + row] = ga.y;
        sA[(l + 32) * 68 + row] = ga.z;
        sA[(l + 48) * 68 + row] = ga.w;
        float4 gb = W4[((size_t)(jc * 64 + row) * ND + kt * 64) / 4 + l];
        sB[(l + 0) * 68 + row] = gb.x;
        sB[(l + 16) * 68 + row] = gb.y;
        sB[(l + 32) * 68 + row] = gb.z;
        sB[(l + 48) * 68 + row] = gb.w;
      }
      __syncthreads();
#pragma unroll 4
      for (int kk = 0; kk < 64; ++kk) {
        float4 a4 = *(const float4*)&sA[kk * 68 + 4 * ti];
        float4 b4 = *(const float4*)&sB[kk * 68 + 4 * tj];
        acc[0][0] += a4.x * b4.x; acc[0][1] += a4.x * b4.y;
        acc[0][2] += a4.x * b4.z; acc[0][3] += a4.x * b4.w;
        acc[1][0] += a4.y * b4.x; acc[1][1] += a4.y * b4.y;
        acc[1][2] += a4.y * b4.z; acc[1][3] += a4.y * b4.w;
        acc[2][0] += a4.z * b4.x; acc[2][1] += a4.z * b4.y;
        acc[2][2] += a4.z * b4.z; acc[2][3] += a4.z * b4.w;
        acc[3][0] += a4.w * b4.x; acc[3][1] += a4.w * b4.y;
        acc[3][2] += a4.w * b4.z; acc[3][3] += a4.w * b4.w;
      }
    }
    // chunk epilogue: h = tanh(acc + q), pu += h*v
    const float4 q4 = *(const float4*)&q_ws[b * ND + jc * 64 + 4 * tj];
    const float4 v4 = *(const float4*)&v[jc * 64 + 4 * tj];
#pragma unroll
    for (int r = 0; r < 4; ++r) {
      float h0 = tanhf(acc[r][0] + q4.x);
      float h1 = tanhf(acc[r][1] + q4.y);
      float h2 = tanhf(acc[r][2] + q4.z);
      float h3 = tanhf(acc[r][3] + q4.w);
      pu[r] += h0 * v4.x + h1 * v4.y + h2 * v4.z + h3 * v4.w;
    }
  }

  // reduce pu across the 16 tj-lanes (contiguous lane groups of 16)
#pragma unroll
  for (int r = 0; r < 4; ++r) {
    float x = pu[r];
    x += __shfl_xor(x, 1, 16);
    x += __shfl_xor(x, 2, 16);
    x += __shfl_xor(x, 4, 16);
    x += __shfl_xor(x, 8, 16);
    pu[r] = x;
  }

  if (tj == 0) {
#pragma unroll
    for (int r = 0; r < 4; ++r) {
      const int srow = 4 * ti + r;
      const float lg = CCLIP * tanhf(pu[r]);
      const float w = __expf(lg - CCLIP) == 0.f ? expf(lg - CCLIP)
                                                : expf(lg - CCLIP);
      out_logit[b * NS + s0 + srow] = lg;
      w_ws[b * NS + s0 + srow] = w;
      wrow[srow] = w;
    }
  }
  __syncthreads();

  // per-block weighted row sum: dp[d] = sum_i wrow[i]*src[b,s0+i,d]
  float a0 = 0.f, a1 = 0.f;
  const float* sb = src + (size_t)(b * NS + s0) * ND;
#pragma unroll 4
  for (int i = 0; i < 64; ++i) {
    const float wv = wrow[i];
    a0 += wv * sb[(size_t)i * ND + tid];
    a1 += wv * sb[(size_t)i * ND + tid + 256];
  }
  dp_ws[(size_t)blk * ND + tid] = a0;
  dp_ws[(size_t)blk * ND + tid + 256] = a1;
}

// ---------------------------------------------------------------------------
// Kernel C: finalize. Per b: S = sum w; probs = w/S; d' = (sum dp partials)/S
// ---------------------------------------------------------------------------
__global__ __launch_bounds__(256) void fin_kernel(
    const float* __restrict__ w_ws, const float* __restrict__ dp_ws,
    float* __restrict__ out_dp, float* __restrict__ out_probs) {
  const int b = blockIdx.x;
  const int tid = threadIdx.x;
  __shared__ float red[4];
  __shared__ float s_inv;

  float x = 0.f;
  for (int idx = tid; idx < NS; idx += 256) x += w_ws[b * NS + idx];
#pragma unroll
  for (int m = 32; m; m >>= 1) x += __shfl_xor(x, m, 64);
  if ((tid & 63) == 0) red[tid >> 6] = x;
  __syncthreads();
  if (tid == 0) s_inv = 1.f / (red[0] + red[1] + red[2] + red[3]);
  __syncthreads();
  const float inv = s_inv;

  for (int idx = tid; idx < NS; idx += 256)
    out_probs[b * NS + idx] = w_ws[b * NS + idx] * inv;

  for (int d = tid; d < ND; d += 256) {
    float acc = 0.f;
#pragma unroll 8
    for (int t = 0; t < 32; ++t) acc += dp_ws[(size_t)(b * 32 + t) * ND + d];
    out_dp[b * ND + d] = acc * inv;
  }
}

// ---------------------------------------------------------------------------
extern "C" void kernel_launch(void* const* d_in, const int* in_sizes, int n_in,
                              void* d_out, int out_size, void* d_ws,
                              size_t ws_size, hipStream_t stream) {
  const float* src = (const float*)d_in[0];   // [64,2048,512]
  const float* tgt = (const float*)d_in[1];   // [64,1,512]
  const float* Wq = (const float*)d_in[2];    // [512,512]
  const float* Wref = (const float*)d_in[3];  // [512,512]
  const float* v = (const float*)d_in[4];     // [512]

  float* out = (float*)d_out;
  float* out_dp = out;                     // 64*512
  float* out_probs = out + NB * ND;        // 64*2048
  float* out_logit = out + NB * ND + NB * NS;

  float* ws = (float*)d_ws;
  float* q_ws = ws;                        // 64*512
  float* w_ws = ws + NB * ND;              // 64*2048
  float* dp_ws = ws + NB * ND + NB * NS;   // 2048*512

  qk_kernel<<<2 * NB, 256, 0, stream>>>(tgt, Wq, q_ws);
  main_kernel<<<NB * 32, 256, 0, stream>>>(src, Wref, v, q_ws, w_ws, dp_ws,
                                           out_logit);
  fin_kernel<<<NB, 256, 0, stream>>>(w_ws, dp_ws, out_dp, out_probs);
}

// Round 3
// 658.701 us; speedup vs baseline: 1.9643x; 1.9643x over previous
//
#include <hip/hip_runtime.h>
#include <math.h>

#define NB 64
#define NS 2048
#define ND 512
#define MTOT (NB * NS)  // 131072
#define CCLIP 10.0f

typedef _Float16 f16x8 __attribute__((ext_vector_type(8)));
typedef _Float16 f16x4 __attribute__((ext_vector_type(4)));
typedef float f32x4 __attribute__((ext_vector_type(4)));

__device__ __forceinline__ void gl2lds16(const void* g, void* l) {
  __builtin_amdgcn_global_load_lds(
      (const __attribute__((address_space(1))) void*)(uintptr_t)g,
      (__attribute__((address_space(3))) void*)(uintptr_t)l, 16, 0, 0);
}

__device__ __forceinline__ float tanh_fast(float x) {
  float e = __expf(2.f * x);
  return 1.f - 2.f * __builtin_amdgcn_rcpf(e + 1.f);
}

// ---------------------------------------------------------------------------
// cvtw: Wref fp32 -> fp16 (512x512). 256 blocks x 256 thr, 1 float4 each.
// ---------------------------------------------------------------------------
__global__ __launch_bounds__(256) void cvtw_kernel(
    const float4* __restrict__ w4, f16x4* __restrict__ wh) {
  const int idx = blockIdx.x * 256 + threadIdx.x;  // < 65536
  float4 x = w4[idx];
  f16x4 o;
  o[0] = (_Float16)x.x; o[1] = (_Float16)x.y;
  o[2] = (_Float16)x.z; o[3] = (_Float16)x.w;
  wh[idx] = o;
}

// ---------------------------------------------------------------------------
// qk: q[b,d] = sum_k W_q[d,k] * tgt[b,k]  (fp32, tiny)
// ---------------------------------------------------------------------------
__global__ __launch_bounds__(256) void qk_kernel(const float* __restrict__ tgt,
                                                 const float* __restrict__ Wq,
                                                 float* __restrict__ q_ws) {
  const int b = blockIdx.x >> 1;
  const int d = ((blockIdx.x & 1) << 8) + threadIdx.x;
  __shared__ float tl[ND];
  tl[threadIdx.x] = tgt[b * ND + threadIdx.x];
  tl[threadIdx.x + 256] = tgt[b * ND + threadIdx.x + 256];
  __syncthreads();
  const float4* wr = (const float4*)(Wq + (size_t)d * ND);
  float acc = 0.f;
#pragma unroll 8
  for (int k4 = 0; k4 < ND / 4; ++k4) {
    float4 w4 = wr[k4];
    acc += w4.x * tl[4 * k4 + 0] + w4.y * tl[4 * k4 + 1] +
           w4.z * tl[4 * k4 + 2] + w4.w * tl[4 * k4 + 3];
  }
  q_ws[b * ND + d] = acc;
}

// ---------------------------------------------------------------------------
// gemm (fused): block = 32 src rows, full K in LDS (fp16, converted on the
// fly), two 256-col passes over Wref-fp16 staged 16KB/kt via global_load_lds.
// Epilogue: u (full, in-block) -> logit, w; dp partials from persistent A LDS.
// LDS: sA 32KB + sB 16KB = 48KB -> 3 blocks/CU.
// ---------------------------------------------------------------------------
__global__ __launch_bounds__(256) void gemm_kernel(
    const float* __restrict__ src, const _Float16* __restrict__ Wh,
    const float* __restrict__ q_ws, const float* __restrict__ v,
    _Float16* __restrict__ dp_h, float* __restrict__ out_logit,
    float* __restrict__ out_probs_w) {
  __shared__ __align__(16) _Float16 sA[64 * 32 * 8];  // [o][row][8] 32 KB
  __shared__ __align__(16) _Float16 sB[4 * 256 * 8];  // [kg][col][8] 16 KB
  float* ured = (float*)(void*)sB;          // 128 floats (aliased, post-MFMA)
  float* wrow = (float*)(void*)sB + 128;    // 32 floats

  const int tid = threadIdx.x;
  const int lane = tid & 63;
  const int w = tid >> 6;
  const int s0 = blockIdx.x << 5;      // 32 rows per block
  const int bb = blockIdx.x >> 6;      // batch index

  // ---- stage A: fp32 -> fp16, [octet][row][8] ----
  {
    const int r = tid >> 3;   // row 0..31
    const int ob = tid & 7;   // octet base
    const float4* sp = (const float4*)(src + (size_t)(s0 + r) * ND);
#pragma unroll
    for (int j = 0; j < 8; ++j) {
      const int o = ob + 8 * j;
      float4 x0 = sp[2 * o];
      float4 x1 = sp[2 * o + 1];
      f16x8 h;
      h[0] = (_Float16)x0.x; h[1] = (_Float16)x0.y;
      h[2] = (_Float16)x0.z; h[3] = (_Float16)x0.w;
      h[4] = (_Float16)x1.x; h[5] = (_Float16)x1.y;
      h[6] = (_Float16)x1.z; h[7] = (_Float16)x1.w;
      *(f16x8*)(sA + ((o << 5) + r) * 8) = h;
    }
  }

  const int quad = lane >> 4;
  const int l15 = lane & 15;

  float pu[2][4] = {{0.f, 0.f, 0.f, 0.f}, {0.f, 0.f, 0.f, 0.f}};

  for (int half = 0; half < 2; ++half) {
    f32x4 acc[2][4];
#pragma unroll
    for (int i = 0; i < 2; ++i)
#pragma unroll
      for (int j = 0; j < 4; ++j) acc[i][j] = (f32x4){0.f, 0.f, 0.f, 0.f};

    // B staging: 16 chunks of 1024B; chunk c = rr*4 + w
    const _Float16* gp[4];
    char* lp[4];
#pragma unroll
    for (int rr = 0; rr < 4; ++rr) {
      const int c = rr * 4 + w;
      const int kg = c >> 2;
      const int col = ((c & 3) << 6) + lane;
      gp[rr] = Wh + ((size_t)(half * 256 + col) << 9) + kg * 8;
      lp[rr] = (char*)sB + c * 1024;
    }

    for (int kt = 0; kt < 16; ++kt) {
      __syncthreads();
#pragma unroll
      for (int rr = 0; rr < 4; ++rr) gl2lds16(gp[rr] + kt * 32, lp[rr]);
      __syncthreads();

      f16x8 af[2], bf[4];
#pragma unroll
      for (int i = 0; i < 2; ++i)
        af[i] = *(const f16x8*)(sA + (((kt * 4 + quad) << 5) + 16 * i + l15) * 8);
#pragma unroll
      for (int j = 0; j < 4; ++j)
        bf[j] = *(const f16x8*)(sB + ((quad << 8) + (w << 6) + 16 * j + l15) * 8);
#pragma unroll
      for (int i = 0; i < 2; ++i)
#pragma unroll
        for (int j = 0; j < 4; ++j)
          acc[i][j] = __builtin_amdgcn_mfma_f32_16x16x32_f16(af[i], bf[j],
                                                             acc[i][j], 0, 0, 0);
    }

    // epilogue for this half: pu[row] += tanh(C + q[d]) * v[d]
#pragma unroll
    for (int j = 0; j < 4; ++j) {
      const int dl = half * 256 + (w << 6) + 16 * j + l15;
      const float qq = q_ws[bb * ND + dl];
      const float vv = v[dl];
#pragma unroll
      for (int i = 0; i < 2; ++i) {
        f32x4 a = acc[i][j];
#pragma unroll
        for (int r = 0; r < 4; ++r) pu[i][r] += tanh_fast(a[r] + qq) * vv;
      }
    }
  }

  // reduce pu across the 16 col-lanes
#pragma unroll
  for (int i = 0; i < 2; ++i)
#pragma unroll
    for (int r = 0; r < 4; ++r) {
      float x = pu[i][r];
      x += __shfl_xor(x, 1, 16);
      x += __shfl_xor(x, 2, 16);
      x += __shfl_xor(x, 4, 16);
      x += __shfl_xor(x, 8, 16);
      pu[i][r] = x;
    }

  __syncthreads();  // all sB frag reads done; safe to alias ured/wrow
  if (l15 == 0) {
#pragma unroll
    for (int i = 0; i < 2; ++i)
#pragma unroll
      for (int r = 0; r < 4; ++r)
        ured[w * 32 + 16 * i + quad * 4 + r] = pu[i][r];
  }
  __syncthreads();
  if (tid < 32) {
    const float u = ured[tid] + ured[32 + tid] + ured[64 + tid] + ured[96 + tid];
    const float lg = CCLIP * tanhf(u);
    out_logit[s0 + tid] = lg;
    const float wv = expf(lg - CCLIP);
    out_probs_w[s0 + tid] = wv;
    wrow[tid] = wv;
  }
  __syncthreads();

  // dp partials from persistent fp16 A in LDS
  {
    const int o0 = tid >> 3;
    const int h0 = tid & 7;
    float a0 = 0.f, a1 = 0.f;
#pragma unroll 8
    for (int s = 0; s < 32; ++s) {
      const float wv = wrow[s];
      a0 += wv * (float)sA[(((o0) << 5) + s) * 8 + h0];
      a1 += wv * (float)sA[(((o0 + 32) << 5) + s) * 8 + h0];
    }
    dp_h[(size_t)blockIdx.x * ND + tid] = (_Float16)a0;
    dp_h[(size_t)blockIdx.x * ND + tid + 256] = (_Float16)a1;
  }
}

// ---------------------------------------------------------------------------
// fin: per b: S = sum w (in out_probs); probs *= 1/S in place;
//      d'[d] = (sum of 64 fp16 partials) / S
// ---------------------------------------------------------------------------
__global__ __launch_bounds__(256) void fin_kernel(
    const _Float16* __restrict__ dp_h, float* __restrict__ out_dp,
    float* __restrict__ out_probs) {
  const int b = blockIdx.x;
  const int tid = threadIdx.x;
  __shared__ float red[4];
  __shared__ float s_inv;

  float x = 0.f;
  for (int idx = tid; idx < NS; idx += 256) x += out_probs[b * NS + idx];
#pragma unroll
  for (int m = 32; m; m >>= 1) x += __shfl_xor(x, m, 64);
  if ((tid & 63) == 0) red[tid >> 6] = x;
  __syncthreads();
  if (tid == 0) s_inv = 1.f / (red[0] + red[1] + red[2] + red[3]);
  __syncthreads();
  const float inv = s_inv;

  for (int idx = tid; idx < NS; idx += 256)
    out_probs[b * NS + idx] *= inv;

  for (int d = tid; d < ND; d += 256) {
    float acc = 0.f;
#pragma unroll 8
    for (int t = 0; t < 64; ++t)
      acc += (float)dp_h[(size_t)(b * 64 + t) * ND + d];
    out_dp[b * ND + d] = acc * inv;
  }
}

// ---------------------------------------------------------------------------
extern "C" void kernel_launch(void* const* d_in, const int* in_sizes, int n_in,
                              void* d_out, int out_size, void* d_ws,
                              size_t ws_size, hipStream_t stream) {
  const float* src = (const float*)d_in[0];   // [64,2048,512]
  const float* tgt = (const float*)d_in[1];   // [64,1,512]
  const float* Wq = (const float*)d_in[2];    // [512,512]
  const float* Wref = (const float*)d_in[3];  // [512,512]
  const float* v = (const float*)d_in[4];     // [512]

  float* out = (float*)d_out;
  float* out_dp = out;                        // 64*512
  float* out_probs = out + NB * ND;           // 64*2048 (holds w pre-fin)
  float* out_logit = out + NB * ND + NB * NS; // 64*2048

  // workspace: 4,849,664 B total (== R1's proven footprint)
  char* ws = (char*)d_ws;
  _Float16* dp_h = (_Float16*)ws;                   // 4096*512*2 = 4,194,304 B
  _Float16* Wh = (_Float16*)(ws + 4194304);         // 512*512*2  =   524,288 B
  float* q_ws = (float*)(ws + 4718592);             // 64*512*4   =   131,072 B

  cvtw_kernel<<<256, 256, 0, stream>>>((const float4*)Wref, (f16x4*)Wh);
  qk_kernel<<<2 * NB, 256, 0, stream>>>(tgt, Wq, q_ws);
  gemm_kernel<<<MTOT / 32, 256, 0, stream>>>(src, Wh, q_ws, v, dp_h,
                                             out_logit, out_probs);
  fin_kernel<<<NB, 256, 0, stream>>>(dp_h, out_dp, out_probs);
}

// Round 4
// 588.366 us; speedup vs baseline: 2.1992x; 1.1195x over previous
//
#include <hip/hip_runtime.h>
#include <math.h>

#define NB 64
#define NS 2048
#define ND 512
#define MTOT (NB * NS)  // 131072
#define CCLIP 10.0f

typedef _Float16 f16x8 __attribute__((ext_vector_type(8)));
typedef _Float16 f16x4 __attribute__((ext_vector_type(4)));
typedef float f32x4 __attribute__((ext_vector_type(4)));

__device__ __forceinline__ void gl2lds16(const void* g, void* l) {
  __builtin_amdgcn_global_load_lds(
      (const __attribute__((address_space(1))) void*)(uintptr_t)g,
      (__attribute__((address_space(3))) void*)(uintptr_t)l, 16, 0, 0);
}

__device__ __forceinline__ float tanh_fast(float x) {
  float e = __expf(2.f * x);
  return 1.f - 2.f * __builtin_amdgcn_rcpf(e + 1.f);
}

// ---------------------------------------------------------------------------
// cvtw: Wref fp32 -> fp16 (512x512). 256 blocks x 256 thr, 1 float4 each.
// ---------------------------------------------------------------------------
__global__ __launch_bounds__(256) void cvtw_kernel(
    const float4* __restrict__ w4, f16x4* __restrict__ wh) {
  const int idx = blockIdx.x * 256 + threadIdx.x;  // < 65536
  float4 x = w4[idx];
  f16x4 o;
  o[0] = (_Float16)x.x; o[1] = (_Float16)x.y;
  o[2] = (_Float16)x.z; o[3] = (_Float16)x.w;
  wh[idx] = o;
}

// ---------------------------------------------------------------------------
// qk: q[b,d] = sum_k W_q[d,k] * tgt[b,k]  (fp32, tiny)
// ---------------------------------------------------------------------------
__global__ __launch_bounds__(256) void qk_kernel(const float* __restrict__ tgt,
                                                 const float* __restrict__ Wq,
                                                 float* __restrict__ q_ws) {
  const int b = blockIdx.x >> 1;
  const int d = ((blockIdx.x & 1) << 8) + threadIdx.x;
  __shared__ float tl[ND];
  tl[threadIdx.x] = tgt[b * ND + threadIdx.x];
  tl[threadIdx.x + 256] = tgt[b * ND + threadIdx.x + 256];
  __syncthreads();
  const float4* wr = (const float4*)(Wq + (size_t)d * ND);
  float acc = 0.f;
#pragma unroll 8
  for (int k4 = 0; k4 < ND / 4; ++k4) {
    float4 w4 = wr[k4];
    acc += w4.x * tl[4 * k4 + 0] + w4.y * tl[4 * k4 + 1] +
           w4.z * tl[4 * k4 + 2] + w4.w * tl[4 * k4 + 3];
  }
  q_ws[b * ND + d] = acc;
}

// ---------------------------------------------------------------------------
// gemm: 128x128 tile, BK=32, 4 waves, wave tile 64x64 (4x4 frags 16x16x32).
// A (src, fp32) converted to fp16 in-kernel: 4 float4 loads + cvt + 2
// ds_write_b128 per thread per kt. B (Wref fp16, L2-resident) staged via
// global_load_lds w16. Epilogue: pu partial = sum_{64-col slab} tanh(C+q)*v.
// LDS: 8 KB sA + 8 KB sB + 1 KB qv = 17 KB.
// ---------------------------------------------------------------------------
__global__ __launch_bounds__(256) void gemm_kernel(
    const float* __restrict__ src, const _Float16* __restrict__ Wh,
    const float* __restrict__ q_ws, const float* __restrict__ v,
    float* __restrict__ pu_ws) {
  __shared__ __align__(16) _Float16 sA[4 * 128 * 8];  // 8 KB [kg][row][8]
  __shared__ __align__(16) _Float16 sB[4 * 128 * 8];  // 8 KB [kg][col][8]
  __shared__ float qv[256];

  const int tid = threadIdx.x;
  const int lane = tid & 63;
  const int w = tid >> 6;
  const int mtile = blockIdx.x >> 2;
  const int ntile = blockIdx.x & 3;
  const int sBlk = mtile << 7;
  const int nBlk = ntile << 7;
  const int bb = sBlk >> 11;

  if (tid < 128) {
    qv[tid] = q_ws[bb * ND + nBlk + tid];
    qv[128 + tid] = v[nBlk + tid];
  }

  const int m0 = (w >> 1) << 6;
  const int n0 = (w & 1) << 6;
  const int quad = lane >> 4;
  const int l15 = lane & 15;

  // A staging: thread -> row (tid&127), k-half (tid>>7)*16
  const int ar = tid & 127;
  const int kh = tid >> 7;
  const float4* ap = (const float4*)(src + ((size_t)(sBlk + ar) << 9)) + kh * 4;
  _Float16* aw0 = sA + ((kh * 2 + 0) * 128 + ar) * 8;
  _Float16* aw1 = sA + ((kh * 2 + 1) * 128 + ar) * 8;

  // B staging: 8 chunks of 1024 B; chunk c = rr*4 + w, kg = c>>1, colh = c&1
  const _Float16* gp[2];
  char* lp[2];
#pragma unroll
  for (int rr = 0; rr < 2; ++rr) {
    const int c = rr * 4 + w;
    const int kg = c >> 1;
    const int colh = c & 1;
    gp[rr] = Wh + ((size_t)(nBlk + colh * 64 + lane) << 9) + kg * 8;
    lp[rr] = (char*)sB + c * 1024;
  }

  f32x4 acc[4][4];
#pragma unroll
  for (int i = 0; i < 4; ++i)
#pragma unroll
    for (int j = 0; j < 4; ++j) acc[i][j] = (f32x4){0.f, 0.f, 0.f, 0.f};

  for (int kt = 0; kt < 16; ++kt) {
    __syncthreads();
    gl2lds16(gp[0] + kt * 32, lp[0]);
    gl2lds16(gp[1] + kt * 32, lp[1]);
    float4 x0 = ap[kt * 8 + 0];
    float4 x1 = ap[kt * 8 + 1];
    float4 x2 = ap[kt * 8 + 2];
    float4 x3 = ap[kt * 8 + 3];
    f16x8 h0, h1;
    h0[0] = (_Float16)x0.x; h0[1] = (_Float16)x0.y;
    h0[2] = (_Float16)x0.z; h0[3] = (_Float16)x0.w;
    h0[4] = (_Float16)x1.x; h0[5] = (_Float16)x1.y;
    h0[6] = (_Float16)x1.z; h0[7] = (_Float16)x1.w;
    h1[0] = (_Float16)x2.x; h1[1] = (_Float16)x2.y;
    h1[2] = (_Float16)x2.z; h1[3] = (_Float16)x2.w;
    h1[4] = (_Float16)x3.x; h1[5] = (_Float16)x3.y;
    h1[6] = (_Float16)x3.z; h1[7] = (_Float16)x3.w;
    *(f16x8*)aw0 = h0;
    *(f16x8*)aw1 = h1;
    __syncthreads();

    f16x8 af[4], bf[4];
#pragma unroll
    for (int i = 0; i < 4; ++i)
      af[i] = *(const f16x8*)(sA + (quad * 128 + m0 + 16 * i + l15) * 8);
#pragma unroll
    for (int j = 0; j < 4; ++j)
      bf[j] = *(const f16x8*)(sB + (quad * 128 + n0 + 16 * j + l15) * 8);
#pragma unroll
    for (int i = 0; i < 4; ++i)
#pragma unroll
      for (int j = 0; j < 4; ++j)
        acc[i][j] = __builtin_amdgcn_mfma_f32_16x16x32_f16(af[i], bf[j],
                                                           acc[i][j], 0, 0, 0);
  }

  // epilogue: pu[row] += tanh(C + q[d]) * v[d] over this wave's 64-col slab
  float pu[4][4];
#pragma unroll
  for (int i = 0; i < 4; ++i)
#pragma unroll
    for (int r = 0; r < 4; ++r) pu[i][r] = 0.f;

#pragma unroll
  for (int j = 0; j < 4; ++j) {
    const int dl = n0 + 16 * j + l15;
    const float qq = qv[dl];
    const float vv = qv[128 + dl];
#pragma unroll
    for (int i = 0; i < 4; ++i) {
      f32x4 a = acc[i][j];
#pragma unroll
      for (int r = 0; r < 4; ++r) pu[i][r] += tanh_fast(a[r] + qq) * vv;
    }
  }

#pragma unroll
  for (int i = 0; i < 4; ++i)
#pragma unroll
    for (int r = 0; r < 4; ++r) {
      float x = pu[i][r];
      x += __shfl_xor(x, 1, 16);
      x += __shfl_xor(x, 2, 16);
      x += __shfl_xor(x, 4, 16);
      x += __shfl_xor(x, 8, 16);
      pu[i][r] = x;
    }

  const int slab = ntile * 2 + (w & 1);
  if (l15 == 0) {
#pragma unroll
    for (int i = 0; i < 4; ++i)
#pragma unroll
      for (int r = 0; r < 4; ++r)
        pu_ws[(size_t)slab * MTOT + sBlk + m0 + 16 * i + quad * 4 + r] =
            pu[i][r];
  }
}

// ---------------------------------------------------------------------------
// ulogit: u = sum of 8 slab partials; logit = C*tanh(u); w = exp(logit-C)
// (w parked in out_probs; fin normalizes in place)
// ---------------------------------------------------------------------------
__global__ __launch_bounds__(256) void ulogit_kernel(
    const float* __restrict__ pu_ws, float* __restrict__ w_out,
    float* __restrict__ out_logit) {
  const int s = blockIdx.x * 256 + threadIdx.x;
  float u = 0.f;
#pragma unroll
  for (int k = 0; k < 8; ++k) u += pu_ws[(size_t)k * MTOT + s];
  const float lg = CCLIP * tanhf(u);
  out_logit[s] = lg;
  w_out[s] = expf(lg - CCLIP);
}

// ---------------------------------------------------------------------------
// dp: partial d'[d] = sum_{s in 256-row chunk} w[s] * src[s,d]  (fp32 stream)
// ---------------------------------------------------------------------------
__global__ __launch_bounds__(256) void dp_kernel(const float* __restrict__ src,
                                                 const float* __restrict__ w_ws,
                                                 float* __restrict__ dp_ws) {
  const int blk = blockIdx.x;  // 512 = NB*8
  const int tid = threadIdx.x;
  const int row0 = blk << 8;
  const float2* base = (const float2*)src + ((size_t)row0 << 8) + tid;
  const float4* wp = (const float4*)(w_ws + row0);
  float a0 = 0.f, a1 = 0.f;
#pragma unroll 4
  for (int s4 = 0; s4 < 64; ++s4) {
    float4 wv = wp[s4];
    float2 x0 = base[(size_t)(4 * s4 + 0) * 256];
    float2 x1 = base[(size_t)(4 * s4 + 1) * 256];
    float2 x2 = base[(size_t)(4 * s4 + 2) * 256];
    float2 x3 = base[(size_t)(4 * s4 + 3) * 256];
    a0 += wv.x * x0.x + wv.y * x1.x + wv.z * x2.x + wv.w * x3.x;
    a1 += wv.x * x0.y + wv.y * x1.y + wv.z * x2.y + wv.w * x3.y;
  }
  dp_ws[((size_t)blk << 9) + tid * 2] = a0;
  dp_ws[((size_t)blk << 9) + tid * 2 + 1] = a1;
}

// ---------------------------------------------------------------------------
// fin: per b: S = sum w (in out_probs); probs *= 1/S; d' = (sum 8 partials)/S
// ---------------------------------------------------------------------------
__global__ __launch_bounds__(256) void fin_kernel(
    const float* __restrict__ dp_ws, float* __restrict__ out_dp,
    float* __restrict__ out_probs) {
  const int b = blockIdx.x;
  const int tid = threadIdx.x;
  __shared__ float red[4];
  __shared__ float s_inv;

  float x = 0.f;
  for (int idx = tid; idx < NS; idx += 256) x += out_probs[b * NS + idx];
#pragma unroll
  for (int m = 32; m; m >>= 1) x += __shfl_xor(x, m, 64);
  if ((tid & 63) == 0) red[tid >> 6] = x;
  __syncthreads();
  if (tid == 0) s_inv = 1.f / (red[0] + red[1] + red[2] + red[3]);
  __syncthreads();
  const float inv = s_inv;

  for (int idx = tid; idx < NS; idx += 256)
    out_probs[b * NS + idx] *= inv;

  for (int d = tid; d < ND; d += 256) {
    float acc = 0.f;
#pragma unroll
    for (int t = 0; t < 8; ++t)
      acc += dp_ws[(size_t)(b * 8 + t) * ND + d];
    out_dp[b * ND + d] = acc * inv;
  }
}

// ---------------------------------------------------------------------------
extern "C" void kernel_launch(void* const* d_in, const int* in_sizes, int n_in,
                              void* d_out, int out_size, void* d_ws,
                              size_t ws_size, hipStream_t stream) {
  const float* src = (const float*)d_in[0];   // [64,2048,512]
  const float* tgt = (const float*)d_in[1];   // [64,1,512]
  const float* Wq = (const float*)d_in[2];    // [512,512]
  const float* Wref = (const float*)d_in[3];  // [512,512]
  const float* v = (const float*)d_in[4];     // [512]

  float* out = (float*)d_out;
  float* out_dp = out;                        // 64*512
  float* out_probs = out + NB * ND;           // 64*2048 (holds w pre-fin)
  float* out_logit = out + NB * ND + NB * NS; // 64*2048

  // workspace: 4,849,664 B total (== R1/R3 proven footprint)
  char* ws = (char*)d_ws;
  float* pu_ws = (float*)ws;                  // 8*131072*4 = 4,194,304 B
  float* dp_ws = (float*)ws;                  // 1,048,576 B (aliases pu_ws;
                                              //  used only after ulogit)
  _Float16* Wh = (_Float16*)(ws + 4194304);   // 512*512*2  =   524,288 B
  float* q_ws = (float*)(ws + 4718592);       // 64*512*4   =   131,072 B

  cvtw_kernel<<<256, 256, 0, stream>>>((const float4*)Wref, (f16x4*)Wh);
  qk_kernel<<<2 * NB, 256, 0, stream>>>(tgt, Wq, q_ws);
  gemm_kernel<<<(MTOT / 128) * 4, 256, 0, stream>>>(src, Wh, q_ws, v, pu_ws);
  ulogit_kernel<<<MTOT / 256, 256, 0, stream>>>(pu_ws, out_probs, out_logit);
  dp_kernel<<<NB * 8, 256, 0, stream>>>(src, out_probs, dp_ws);
  fin_kernel<<<NB, 256, 0, stream>>>(dp_ws, out_dp, out_probs);
}

// Round 5
// 480.943 us; speedup vs baseline: 2.6904x; 1.2234x over previous
//
#include <hip/hip_runtime.h>
#include <math.h>

#define NB 64
#define NS 2048
#define ND 512
#define MTOT (NB * NS)  // 131072
#define CCLIP 10.0f

typedef _Float16 f16x8 __attribute__((ext_vector_type(8)));
typedef _Float16 f16x4 __attribute__((ext_vector_type(4)));
typedef float f32x4 __attribute__((ext_vector_type(4)));

__device__ __forceinline__ void gl2lds16(const void* g, void* l) {
  __builtin_amdgcn_global_load_lds(
      (const __attribute__((address_space(1))) void*)(uintptr_t)g,
      (__attribute__((address_space(3))) void*)(uintptr_t)l, 16, 0, 0);
}

__device__ __forceinline__ float tanh_fast(float x) {
  float e = __expf(2.f * x);
  return 1.f - 2.f * __builtin_amdgcn_rcpf(e + 1.f);
}

// ---------------------------------------------------------------------------
// cvtw: Wref fp32 -> fp16 permuted into the exact LDS-staging order:
//   WhA[((kt*4 + kg)*512 + d)*8 + h] = Wref[d][kt*32 + kg*8 + h]
// so gemm's per-kt B staging is one contiguous 32 KB chunk.
// ---------------------------------------------------------------------------
__global__ __launch_bounds__(256) void cvtw_kernel(
    const float4* __restrict__ w4, _Float16* __restrict__ WhA) {
  const int idx = blockIdx.x * 256 + threadIdx.x;  // < 65536 float4s
  const int d = idx >> 7;
  const int k = (idx & 127) << 2;  // k of first element
  float4 x = w4[idx];
  f16x4 o;
  o[0] = (_Float16)x.x; o[1] = (_Float16)x.y;
  o[2] = (_Float16)x.z; o[3] = (_Float16)x.w;
  const int kt = k >> 5;
  const int kg = (k >> 3) & 3;
  const int h = k & 7;  // 0 or 4
  *(f16x4*)(WhA + ((size_t)((kt * 4 + kg) * 512 + d) * 8 + h)) = o;
}

// ---------------------------------------------------------------------------
// qk: q[b,d] = sum_k W_q[d,k] * tgt[b,k]  (fp32, tiny)
// ---------------------------------------------------------------------------
__global__ __launch_bounds__(256) void qk_kernel(const float* __restrict__ tgt,
                                                 const float* __restrict__ Wq,
                                                 float* __restrict__ q_ws) {
  const int b = blockIdx.x >> 1;
  const int d = ((blockIdx.x & 1) << 8) + threadIdx.x;
  __shared__ float tl[ND];
  tl[threadIdx.x] = tgt[b * ND + threadIdx.x];
  tl[threadIdx.x + 256] = tgt[b * ND + threadIdx.x + 256];
  __syncthreads();
  const float4* wr = (const float4*)(Wq + (size_t)d * ND);
  float acc = 0.f;
#pragma unroll 8
  for (int k4 = 0; k4 < ND / 4; ++k4) {
    float4 w4 = wr[k4];
    acc += w4.x * tl[4 * k4 + 0] + w4.y * tl[4 * k4 + 1] +
           w4.z * tl[4 * k4 + 2] + w4.w * tl[4 * k4 + 3];
  }
  q_ws[b * ND + d] = acc;
}

// ---------------------------------------------------------------------------
// gemm: block = 64 src rows x FULL N=512, K=512 in 16 kt of 32.
// 4 waves; wave tile 64 rows x 128 cols -> acc[4][8] f32x4, 32 MFMA/wave/kt.
// A: fp32 src -> fp16 LDS in-kernel (2 float4 + cvt + ds_write_b128/thread).
// B: pre-permuted fp16, one contiguous 32 KB chunk per kt via gl2lds w16.
// u completes in-block -> logit + w written directly (no ulogit pass).
// LDS: sA 4 KB + sB 32 KB + ured 1 KB = 37 KB.
// ---------------------------------------------------------------------------
__global__ __launch_bounds__(256, 2) void gemm_kernel(
    const float* __restrict__ src, const _Float16* __restrict__ WhA,
    const float* __restrict__ q_ws, const float* __restrict__ v,
    float* __restrict__ out_logit, float* __restrict__ out_probs_w) {
  __shared__ __align__(16) _Float16 sA[4 * 64 * 8];   // 4 KB  [kg][row][8]
  __shared__ __align__(16) _Float16 sB[4 * 512 * 8];  // 32 KB [kg][col][8]
  __shared__ float ured[4 * 64];                      // 1 KB

  const int tid = threadIdx.x;
  const int lane = tid & 63;
  const int w = tid >> 6;       // col-quarter 0..3
  const int s0 = blockIdx.x << 6;
  const int bb = blockIdx.x >> 5;

  const int quad = lane >> 4;
  const int l15 = lane & 15;

  // A staging mapping: thread -> (row = tid&63, kg = tid>>6)
  const int ar = tid & 63;
  const int akg = tid >> 6;
  const float4* ap =
      (const float4*)(src + ((size_t)(s0 + ar) << 9)) + akg * 2;
  _Float16* aw = sA + (akg * 64 + ar) * 8;

  const char* gB = (const char*)WhA;

  f32x4 acc[4][8];
#pragma unroll
  for (int i = 0; i < 4; ++i)
#pragma unroll
    for (int j = 0; j < 8; ++j) acc[i][j] = (f32x4){0.f, 0.f, 0.f, 0.f};

  for (int kt = 0; kt < 16; ++kt) {
    __syncthreads();
    // B: 8 x 1KB chunks per wave, contiguous global
#pragma unroll
    for (int i = 0; i < 8; ++i) {
      const int c = w * 8 + i;
      gl2lds16(gB + (size_t)kt * 32768 + c * 1024 + lane * 16,
               (char*)sB + c * 1024);
    }
    // A: one 128-B line per row per kt, fully consumed
    float4 x0 = ap[kt * 8];
    float4 x1 = ap[kt * 8 + 1];
    f16x8 h;
    h[0] = (_Float16)x0.x; h[1] = (_Float16)x0.y;
    h[2] = (_Float16)x0.z; h[3] = (_Float16)x0.w;
    h[4] = (_Float16)x1.x; h[5] = (_Float16)x1.y;
    h[6] = (_Float16)x1.z; h[7] = (_Float16)x1.w;
    *(f16x8*)aw = h;
    __syncthreads();

    f16x8 af[4], bf[8];
#pragma unroll
    for (int i = 0; i < 4; ++i)
      af[i] = *(const f16x8*)(sA + (quad * 64 + 16 * i + l15) * 8);
#pragma unroll
    for (int j = 0; j < 8; ++j)
      bf[j] = *(const f16x8*)(sB + (quad * 512 + w * 128 + 16 * j + l15) * 8);
#pragma unroll
    for (int i = 0; i < 4; ++i)
#pragma unroll
      for (int j = 0; j < 8; ++j)
        acc[i][j] = __builtin_amdgcn_mfma_f32_16x16x32_f16(af[i], bf[j],
                                                           acc[i][j], 0, 0, 0);
  }

  // epilogue: pu[row] = sum over this wave's 128 cols of tanh(C+q)*v
  float pu[4][4];
#pragma unroll
  for (int i = 0; i < 4; ++i)
#pragma unroll
    for (int r = 0; r < 4; ++r) pu[i][r] = 0.f;

#pragma unroll
  for (int j = 0; j < 8; ++j) {
    const int dl = w * 128 + 16 * j + l15;
    const float qq = q_ws[bb * ND + dl];
    const float vv = v[dl];
#pragma unroll
    for (int i = 0; i < 4; ++i) {
      f32x4 a = acc[i][j];
#pragma unroll
      for (int r = 0; r < 4; ++r) pu[i][r] += tanh_fast(a[r] + qq) * vv;
    }
  }

#pragma unroll
  for (int i = 0; i < 4; ++i)
#pragma unroll
    for (int r = 0; r < 4; ++r) {
      float x = pu[i][r];
      x += __shfl_xor(x, 1, 16);
      x += __shfl_xor(x, 2, 16);
      x += __shfl_xor(x, 4, 16);
      x += __shfl_xor(x, 8, 16);
      pu[i][r] = x;
    }

  if (l15 == 0) {
#pragma unroll
    for (int i = 0; i < 4; ++i)
#pragma unroll
      for (int r = 0; r < 4; ++r)
        ured[w * 64 + 16 * i + quad * 4 + r] = pu[i][r];
  }
  __syncthreads();
  if (tid < 64) {
    const float u =
        ured[tid] + ured[64 + tid] + ured[128 + tid] + ured[192 + tid];
    const float lg = CCLIP * tanhf(u);
    out_logit[s0 + tid] = lg;
    out_probs_w[s0 + tid] = expf(lg - CCLIP);
  }
}

// ---------------------------------------------------------------------------
// dp: partial d'[d-half] over a 256-row chunk. 1024 blocks.
//   blk -> b = blk>>4, ch = (blk>>1)&7, half = blk&1
// ---------------------------------------------------------------------------
__global__ __launch_bounds__(256) void dp_kernel(const float* __restrict__ src,
                                                 const float* __restrict__ w_ws,
                                                 float* __restrict__ dp_ws) {
  const int blk = blockIdx.x;
  const int b = blk >> 4;
  const int ch = (blk >> 1) & 7;
  const int half = blk & 1;
  const int tid = threadIdx.x;
  const int row0 = b * NS + ch * 256;
  const float* base = src + ((size_t)row0 << 9) + (half << 8) + tid;
  float a = 0.f;
#pragma unroll 8
  for (int s = 0; s < 256; ++s) a += w_ws[row0 + s] * base[(size_t)s << 9];
  dp_ws[(size_t)blk * 256 + tid] = a;
}

// ---------------------------------------------------------------------------
// fin: per b: S = sum w (parked in out_probs); probs *= 1/S;
//      d'[d] = (sum of 8 chunk partials)/S
// ---------------------------------------------------------------------------
__global__ __launch_bounds__(256) void fin_kernel(
    const float* __restrict__ dp_ws, float* __restrict__ out_dp,
    float* __restrict__ out_probs) {
  const int b = blockIdx.x;
  const int tid = threadIdx.x;
  __shared__ float red[4];
  __shared__ float s_inv;

  float x = 0.f;
  for (int idx = tid; idx < NS; idx += 256) x += out_probs[b * NS + idx];
#pragma unroll
  for (int m = 32; m; m >>= 1) x += __shfl_xor(x, m, 64);
  if ((tid & 63) == 0) red[tid >> 6] = x;
  __syncthreads();
  if (tid == 0) s_inv = 1.f / (red[0] + red[1] + red[2] + red[3]);
  __syncthreads();
  const float inv = s_inv;

  for (int idx = tid; idx < NS; idx += 256)
    out_probs[b * NS + idx] *= inv;

  for (int d = tid; d < ND; d += 256) {
    const int half = d >> 8;
    const int dl = d & 255;
    float acc = 0.f;
#pragma unroll
    for (int ch = 0; ch < 8; ++ch)
      acc += dp_ws[(size_t)(((b * 8 + ch) << 1) + half) * 256 + dl];
    out_dp[b * ND + d] = acc * inv;
  }
}

// ---------------------------------------------------------------------------
extern "C" void kernel_launch(void* const* d_in, const int* in_sizes, int n_in,
                              void* d_out, int out_size, void* d_ws,
                              size_t ws_size, hipStream_t stream) {
  const float* src = (const float*)d_in[0];   // [64,2048,512]
  const float* tgt = (const float*)d_in[1];   // [64,1,512]
  const float* Wq = (const float*)d_in[2];    // [512,512]
  const float* Wref = (const float*)d_in[3];  // [512,512]
  const float* v = (const float*)d_in[4];     // [512]

  float* out = (float*)d_out;
  float* out_dp = out;                        // 64*512
  float* out_probs = out + NB * ND;           // 64*2048 (holds w pre-fin)
  float* out_logit = out + NB * ND + NB * NS; // 64*2048

  // workspace: 1,703,936 B total (well under proven 4.85 MB footprint)
  char* ws = (char*)d_ws;
  _Float16* WhA = (_Float16*)ws;              // 512*512*2 =   524,288 B
  float* q_ws = (float*)(ws + 524288);        // 64*512*4  =   131,072 B
  float* dp_ws = (float*)(ws + 655360);       // 1024*256*4 = 1,048,576 B

  cvtw_kernel<<<256, 256, 0, stream>>>((const float4*)Wref, WhA);
  qk_kernel<<<2 * NB, 256, 0, stream>>>(tgt, Wq, q_ws);
  gemm_kernel<<<MTOT / 64, 256, 0, stream>>>(src, WhA, q_ws, v, out_logit,
                                             out_probs);
  dp_kernel<<<NB * 16, 256, 0, stream>>>(src, out_probs, dp_ws);
  fin_kernel<<<NB, 256, 0, stream>>>(dp_ws, out_dp, out_probs);
}